// Round 2
// baseline (1368.344 us; speedup 1.0000x reference)
//
#include <hip/hip_runtime.h>
#include <hip/hip_bf16.h>
#include <stdint.h>

// ---------------------------------------------------------------------------
// NETWORK_OF_DANS: 3 GEMM(+concat-K skip) kernels with the shared per-node
// MLP ("DAN") fused into the epilogue. GEMMs use split-bf16 (hi+lo) 3-term
// MFMA for fp32-equivalent accuracy. Workspace use: 4 MiB (h0, h1 only).
// ---------------------------------------------------------------------------

typedef __attribute__((ext_vector_type(8))) short bf16x8;   // 8 bf16 = 4 VGPR
typedef __attribute__((ext_vector_type(4))) float f32x4;    // MFMA acc

#define MFMA16(a, b, c) __builtin_amdgcn_mfma_f32_16x16x32_bf16((a), (b), (c), 0, 0, 0)

// Split two fp32 into packed bf16 hi (truncated) and bf16 lo (residual).
// hi+lo reproduces x to ~2^-16 relative.
__device__ __forceinline__ void cvt_pair(float x0, float x1, uint32_t& hi, uint32_t& lo) {
    uint32_t u0 = __float_as_uint(x0), u1 = __float_as_uint(x1);
    float r0 = x0 - __uint_as_float(u0 & 0xFFFF0000u);
    float r1 = x1 - __uint_as_float(u1 & 0xFFFF0000u);
    hi = (u0 >> 16) | (u1 & 0xFFFF0000u);
    lo = (__float_as_uint(r0) >> 16) | (__float_as_uint(r1) & 0xFFFF0000u);
}

// Stage a 256x64 fp32 tile -> two XOR-swizzled bf16 [256][64] LDS tiles (hi,lo).
// 512 threads, 4 chunks each; chunk = 8 consecutive k (32B), coalesced 256B/row.
__device__ __forceinline__ void stage_tile(const float* __restrict__ src, int row_base,
                                           int koff, char* hiT, char* loT, int tid) {
#pragma unroll
    for (int j = 0; j < 4; ++j) {
        int c  = tid + 512 * j;      // 0..2047 chunks
        int r  = c >> 3;             // tile row 0..255
        int c8 = c & 7;              // 8-float chunk within the 64-wide row
        const float* g = src + (size_t)(row_base + r) * 1024 + koff + c8 * 8;
        float4 v0 = *(const float4*)g;
        float4 v1 = *(const float4*)(g + 4);
        uint4 hi, lo;
        cvt_pair(v0.x, v0.y, hi.x, lo.x);
        cvt_pair(v0.z, v0.w, hi.y, lo.y);
        cvt_pair(v1.x, v1.y, hi.z, lo.z);
        cvt_pair(v1.z, v1.w, hi.w, lo.w);
        // row stride 128 B; 16B-chunk XOR'd with (row&7) -> conflict-free b128 reads
        int wb = r * 128 + ((c8 * 16) ^ ((r & 7) << 4));
        *(uint4*)(hiT + wb) = hi;
        *(uint4*)(loT + wb) = lo;
    }
}

// C = A(MxK) * W^T (W is [N][K] row-major), M=512 (2 m-tiles), N=32768, tile 256x256.
// Concat-K: k-tiles [0,ksplit) come from (A0,W0), rest from (A1,W1), both lda/ldw=1024.
// Epilogue: per-node 32->15->8->1 leaky-relu MLP, output [512][1024].
__global__ __launch_bounds__(512, 2) void gemm_dan(
    const float* __restrict__ A0, const float* __restrict__ A1,
    const float* __restrict__ W0, const float* __restrict__ W1,
    const float* __restrict__ bias0, const float* __restrict__ bias1,
    const float* __restrict__ Dw1, const float* __restrict__ Db1,
    const float* __restrict__ Dw2, const float* __restrict__ Db2,
    const float* __restrict__ Dw3, const float* __restrict__ Db3,
    float* __restrict__ out, int ktiles, int ksplit, int layer)
{
    extern __shared__ char lds[];
    char* Ahi = lds;
    char* Alo = lds + 32 * 1024;
    char* Whi = lds + 64 * 1024;
    char* Wlo = lds + 96 * 1024;

    const int tid  = threadIdx.x;
    const int lane = tid & 63;
    const int wave = tid >> 6;       // 0..7
    const int wr   = wave >> 2;      // 0..1  -> 128-row half
    const int wc   = wave & 3;       // 0..3  -> 64-col quarter
    const int mt   = blockIdx.x & 1;   // m tile (0..1)
    const int nt   = blockIdx.x >> 1;  // n tile (0..127)
    const int l15  = lane & 15;
    const int lg   = lane >> 4;

    f32x4 acc[8][4] = {};            // 8 m-frags x 4 n-frags x 4 f32 = 128 VGPR

    for (int kt = 0; kt < ktiles; ++kt) {
        const float* As; const float* Ws; int koff;
        if (kt < ksplit) { As = A0; Ws = W0; koff = kt * 64; }
        else             { As = A1; Ws = W1; koff = (kt - ksplit) * 64; }

        stage_tile(As, mt * 256, koff, Ahi, Alo, tid);
        stage_tile(Ws, nt * 256, koff, Whi, Wlo, tid);
        __syncthreads();

#pragma unroll
        for (int ks = 0; ks < 2; ++ks) {          // two K=32 steps per BK=64
            const int cb = ks * 64 + (lg << 4);   // byte col of this lane-group's 8 k's
            bf16x8 bh[4], bl[4];
#pragma unroll
            for (int fn = 0; fn < 4; ++fn) {
                int row = wc * 64 + fn * 16 + l15;            // W-tile row = n
                int off = row * 128 + (cb ^ ((row & 7) << 4));
                bh[fn] = *(const bf16x8*)(Whi + off);
                bl[fn] = *(const bf16x8*)(Wlo + off);
            }
#pragma unroll
            for (int fm = 0; fm < 8; ++fm) {
                int row = wr * 128 + fm * 16 + l15;           // A-tile row = m
                int off = row * 128 + (cb ^ ((row & 7) << 4));
                bf16x8 ah = *(const bf16x8*)(Ahi + off);
                bf16x8 al = *(const bf16x8*)(Alo + off);
#pragma unroll
                for (int fn = 0; fn < 4; ++fn) {
                    acc[fm][fn] = MFMA16(ah, bh[fn], acc[fm][fn]);  // hi*hi
                    acc[fm][fn] = MFMA16(ah, bl[fn], acc[fm][fn]);  // hi*lo
                    acc[fm][fn] = MFMA16(al, bh[fn], acc[fm][fn]);  // lo*hi
                }
            }
        }
        __syncthreads();
    }

    // ---- Fused DAN epilogue -------------------------------------------------
    // Tile covers batch rows [mt*256, +256) x nodes [nt*8, +8) (8 nodes x 32 ch).
    // Two 128-row halves through 128 KiB LDS (reused). Swizzle: float col
    // c -> c ^ ((r&7)<<2) (16B-chunk XOR), same involution on write and read.
    float* fl = (float*)lds;
#pragma unroll 1
    for (int half = 0; half < 2; ++half) {
        __syncthreads();
        if (wr == half) {
            // C/D frag layout: col=lane&15, row=(lane>>4)*4+j (m89-verified)
#pragma unroll
            for (int fm = 0; fm < 8; ++fm)
#pragma unroll
                for (int fn = 0; fn < 4; ++fn)
#pragma unroll
                    for (int j = 0; j < 4; ++j) {
                        int r = fm * 16 + lg * 4 + j;        // 0..127
                        int c = wc * 64 + fn * 16 + l15;     // 0..255
                        fl[r * 256 + (c ^ ((r & 7) << 2))] = acc[fm][fn][j];
                    }
        }
        __syncthreads();
        // 128 rows x 8 nodes = 1024 outputs; 512 threads -> 2 each
#pragma unroll 1
        for (int t = 0; t < 2; ++t) {
            int idx = tid + t * 512;
            int r   = idx >> 3;                  // 0..127 (row within half)
            int nd  = idx & 7;                   // node within tile
            int node = nt * 8 + nd;

            float z[32];
            const float* q0 = bias0 + node * 32;
#pragma unroll
            for (int q = 0; q < 8; ++q) {
                int cf = (nd * 32 + q * 4) ^ ((r & 7) << 2);
                float4 v  = *(const float4*)(fl + r * 256 + cf);
                float4 bb = *(const float4*)(q0 + q * 4);
                z[q * 4 + 0] = v.x + bb.x;
                z[q * 4 + 1] = v.y + bb.y;
                z[q * 4 + 2] = v.z + bb.z;
                z[q * 4 + 3] = v.w + bb.w;
            }
            if (bias1 != nullptr) {
                const float* q1 = bias1 + node * 32;
#pragma unroll
                for (int q = 0; q < 8; ++q) {
                    float4 bb = *(const float4*)(q1 + q * 4);
                    z[q * 4 + 0] += bb.x; z[q * 4 + 1] += bb.y;
                    z[q * 4 + 2] += bb.z; z[q * 4 + 3] += bb.w;
                }
            }

            float h1v[15];
#pragma unroll
            for (int j = 0; j < 15; ++j) {
                // one-hot layer code == adding column (32+layer) of Dw1 to bias
                float a = Db1[j] + Dw1[j * 35 + 32 + layer];
#pragma unroll
                for (int c = 0; c < 32; ++c) a += z[c] * Dw1[j * 35 + c];
                h1v[j] = fmaxf(a, 0.01f * a);
            }
            float h2v[8];
#pragma unroll
            for (int j = 0; j < 8; ++j) {
                float a = Db2[j];
#pragma unroll
                for (int c = 0; c < 15; ++c) a += h1v[c] * Dw2[j * 15 + c];
                h2v[j] = fmaxf(a, 0.01f * a);
            }
            float o = Db3[0];
#pragma unroll
            for (int c = 0; c < 8; ++c) o += h2v[c] * Dw3[c];

            int rg = mt * 256 + half * 128 + r;
            out[(size_t)rg * 1024 + node] = fmaxf(o, 0.01f * o);
        }
    }
}

extern "C" void kernel_launch(void* const* d_in, const int* in_sizes, int n_in,
                              void* d_out, int out_size, void* d_ws, size_t ws_size,
                              hipStream_t stream) {
    const float* x    = (const float*)d_in[0];
    const float* W0   = (const float*)d_in[1];
    const float* b0   = (const float*)d_in[2];
    const float* W1   = (const float*)d_in[3];
    const float* b1   = (const float*)d_in[4];
    const float* W2   = (const float*)d_in[5];
    const float* b2   = (const float*)d_in[6];
    const float* Ws02 = (const float*)d_in[7];
    const float* bs02 = (const float*)d_in[8];
    const float* Ws13 = (const float*)d_in[9];
    const float* bs13 = (const float*)d_in[10];
    const float* Dw1  = (const float*)d_in[11];
    const float* Db1  = (const float*)d_in[12];
    const float* Dw2  = (const float*)d_in[13];
    const float* Db2  = (const float*)d_in[14];
    const float* Dw3  = (const float*)d_in[15];
    const float* Db3  = (const float*)d_in[16];
    float* out = (float*)d_out;

    // workspace: h0 [512][1024] f32 (2 MiB) | h1 (2 MiB)
    float* h0 = (float*)d_ws;
    float* h1 = h0 + 512 * 1024;

    const dim3 gg(256), gb(512);       // (512/256)*(32768/256) output tiles
    const size_t LDS = 128 * 1024;

    // layer 0: pre0 = x*W0^T        -> DAN(l=0) -> h0
    gemm_dan<<<gg, gb, LDS, stream>>>(x, nullptr, W0, nullptr, b0, nullptr,
                                      Dw1, Db1, Dw2, Db2, Dw3, Db3, h0, 16, 16, 0);
    // layer 1: pre1 = h0*W1^T + x*Ws02^T (concat-K) -> DAN(l=1) -> h1
    gemm_dan<<<gg, gb, LDS, stream>>>(h0, x, W1, Ws02, b1, bs02,
                                      Dw1, Db1, Dw2, Db2, Dw3, Db3, h1, 32, 16, 1);
    // layer 2: pre2 = h1*W2^T + h0*Ws13^T (concat-K) -> DAN(l=2) -> out
    gemm_dan<<<gg, gb, LDS, stream>>>(h1, h0, W2, Ws13, b2, bs13,
                                      Dw1, Db1, Dw2, Db2, Dw3, Db3, out, 32, 16, 2);
}

// Round 3
// 1088.078 us; speedup vs baseline: 1.2576x; 1.2576x over previous
//
#include <hip/hip_runtime.h>
#include <hip/hip_bf16.h>
#include <stdint.h>

// ---------------------------------------------------------------------------
// NETWORK_OF_DANS: 3 GEMM(+concat-K skip) kernels, DAN MLP fused in epilogue.
// Split-bf16 (hi+lo) 3-term MFMA for fp32-equivalent accuracy.
// This round: BK=32 double-buffered LDS pipeline (T3 2-phase + T5 setprio):
//   per K-tile: {cvt+ds_write next tile | issue loads tile+2} -> {MFMA} -> bar
// ---------------------------------------------------------------------------

typedef __attribute__((ext_vector_type(8))) short bf16x8;   // 8 bf16 = 4 VGPR
typedef __attribute__((ext_vector_type(4))) float f32x4;    // MFMA acc

#define MFMA16(a, b, c) __builtin_amdgcn_mfma_f32_16x16x32_bf16((a), (b), (c), 0, 0, 0)

// Split two fp32 into packed bf16 hi (truncated) + bf16 lo (residual).
__device__ __forceinline__ void cvt_pair(float x0, float x1, uint32_t& hi, uint32_t& lo) {
    uint32_t u0 = __float_as_uint(x0), u1 = __float_as_uint(x1);
    float r0 = x0 - __uint_as_float(u0 & 0xFFFF0000u);
    float r1 = x1 - __uint_as_float(u1 & 0xFFFF0000u);
    hi = (u0 >> 16) | (u1 & 0xFFFF0000u);
    lo = (__float_as_uint(r0) >> 16) | (__float_as_uint(r1) & 0xFFFF0000u);
}

// LDS tile: [256 rows][32 bf16 = 64 B]; 16B-slot XOR swizzle, 2-way worst case.
// Same involution on write and read (rule #21).
__device__ __forceinline__ int sw(int r, int cb) {
    return r * 64 + (cb ^ (((r >> 1) & 3) << 4));
}

// Buffer layout (64 KiB): Ahi 0 | Alo 16K | Whi 32K | Wlo 48K.  (256x32 bf16 each)

// Issue global loads for one 256x32 A-tile + W-tile into 8 float4 regs.
// chunk c (0..1023 per tile): r=c>>2, c4=c&3 -> 8 floats at col c4*8.
__device__ __forceinline__ void load_pf(const float* __restrict__ As,
                                        const float* __restrict__ Ws,
                                        int arow, int wrow, int koff, int tid,
                                        float4* pf) {
#pragma unroll
    for (int j = 0; j < 2; ++j) {
        int c = tid + 512 * j, r = c >> 2, c4 = c & 3;
        const float* g = As + (size_t)(arow + r) * 1024 + koff + c4 * 8;
        pf[j * 2 + 0] = *(const float4*)g;
        pf[j * 2 + 1] = *(const float4*)(g + 4);
    }
#pragma unroll
    for (int j = 0; j < 2; ++j) {
        int c = tid + 512 * j, r = c >> 2, c4 = c & 3;
        const float* g = Ws + (size_t)(wrow + r) * 1024 + koff + c4 * 8;
        pf[4 + j * 2 + 0] = *(const float4*)g;
        pf[4 + j * 2 + 1] = *(const float4*)(g + 4);
    }
}

// cvt to bf16 hi/lo and write into LDS buffer (waits vmcnt via first use).
__device__ __forceinline__ void store_pf(const float4* pf, char* buf, int tid) {
#pragma unroll
    for (int half = 0; half < 2; ++half) {          // 0: A, 1: W
        char* hiT = buf + half * 32768;
        char* loT = hiT + 16384;
#pragma unroll
        for (int j = 0; j < 2; ++j) {
            int c = tid + 512 * j, r = c >> 2, c4 = c & 3;
            const float4 v0 = pf[half * 4 + j * 2 + 0];
            const float4 v1 = pf[half * 4 + j * 2 + 1];
            uint4 hi, lo;
            cvt_pair(v0.x, v0.y, hi.x, lo.x);
            cvt_pair(v0.z, v0.w, hi.y, lo.y);
            cvt_pair(v1.x, v1.y, hi.z, lo.z);
            cvt_pair(v1.z, v1.w, hi.w, lo.w);
            int wb = sw(r, c4 * 16);
            *(uint4*)(hiT + wb) = hi;
            *(uint4*)(loT + wb) = lo;
        }
    }
}

// C = A(512xK) * W^T (W [N=32768][K]), tile 256x256, BK=32, concat-K skip.
// Epilogue: per-node 32->15->8->1 leaky-relu MLP, output [512][1024].
__global__ __launch_bounds__(512, 2) void gemm_dan(
    const float* __restrict__ A0, const float* __restrict__ A1,
    const float* __restrict__ W0, const float* __restrict__ W1,
    const float* __restrict__ bias0, const float* __restrict__ bias1,
    const float* __restrict__ Dw1, const float* __restrict__ Db1,
    const float* __restrict__ Dw2, const float* __restrict__ Db2,
    const float* __restrict__ Dw3, const float* __restrict__ Db3,
    float* __restrict__ out, int ktiles, int ksplit, int layer)
{
    extern __shared__ char lds[];

    const int tid  = threadIdx.x;
    const int lane = tid & 63;
    const int wave = tid >> 6;       // 0..7
    const int wr   = wave >> 2;      // 0..1  -> 128-row half
    const int wc   = wave & 3;       // 0..3  -> 64-col quarter
    const int mt   = blockIdx.x & 1;   // m tile (0..1)
    const int nt   = blockIdx.x >> 1;  // n tile (0..127)
    const int l15  = lane & 15;
    const int lg   = lane >> 4;
    const int arow = mt * 256, wrow = nt * 256;

    f32x4 acc[8][4] = {};            // 128 VGPR
    float4 pf[8];                    // 32 VGPR in-flight staging regs

    // ---- prologue: stage tile 0 directly, issue loads for tile 1 ----------
    {
        const float* As = A0; const float* Ws = W0; int koff = 0;
        load_pf(As, Ws, arow, wrow, koff, tid, pf);
        store_pf(pf, lds, tid);
        // issue tile 1 loads (land during kt=0 compute)
        if (1 < ksplit) { As = A0; Ws = W0; koff = 32; }
        else            { As = A1; Ws = W1; koff = 0;  }
        load_pf(As, Ws, arow, wrow, koff, tid, pf);
    }
    __syncthreads();

    for (int kt = 0; kt < ktiles; ++kt) {
        char* buf = lds + (size_t)(kt & 1) * 65536;

        // phase (a): finish staging tile kt+1 into buf^1, issue loads kt+2
        if (kt + 1 < ktiles) {
            store_pf(pf, lds + (size_t)((kt + 1) & 1) * 65536, tid);
            int t2 = kt + 2;
            if (t2 < ktiles) {
                const float* As; const float* Ws; int koff;
                if (t2 < ksplit) { As = A0; Ws = W0; koff = t2 * 32; }
                else             { As = A1; Ws = W1; koff = (t2 - ksplit) * 32; }
                load_pf(As, Ws, arow, wrow, koff, tid, pf);
            }
        }

        // phase (b): fragment reads + MFMA cluster
        const int cb = lg << 4;      // this lane-group's 16B (8 k) within 64B row
        const char* Whi = buf + 32768;
        const char* Wlo = buf + 49152;
        bf16x8 bh[4], bl[4];
#pragma unroll
        for (int fn = 0; fn < 4; ++fn) {
            int row = wc * 64 + fn * 16 + l15;               // W row = n
            int off = sw(row, cb);
            bh[fn] = *(const bf16x8*)(Whi + off);
            bl[fn] = *(const bf16x8*)(Wlo + off);
        }
        __builtin_amdgcn_s_setprio(1);
#pragma unroll
        for (int fm = 0; fm < 8; ++fm) {
            int row = wr * 128 + fm * 16 + l15;              // A row = m
            int off = sw(row, cb);
            bf16x8 ah = *(const bf16x8*)(buf + off);
            bf16x8 al = *(const bf16x8*)(buf + 16384 + off);
#pragma unroll
            for (int fn = 0; fn < 4; ++fn) {
                acc[fm][fn] = MFMA16(ah, bh[fn], acc[fm][fn]);  // hi*hi
                acc[fm][fn] = MFMA16(ah, bl[fn], acc[fm][fn]);  // hi*lo
                acc[fm][fn] = MFMA16(al, bh[fn], acc[fm][fn]);  // lo*hi
            }
        }
        __builtin_amdgcn_s_setprio(0);
        __syncthreads();
    }

    // ---- Fused DAN epilogue ------------------------------------------------
    // Tile = batch rows [mt*256,+256) x nodes [nt*8,+8) (8 nodes x 32 ch).
    // Two 128-row halves through LDS; float-col swizzle c ^ ((r&7)<<2).
    float* fl = (float*)lds;
#pragma unroll 1
    for (int half = 0; half < 2; ++half) {
        __syncthreads();
        if (wr == half) {
            // C/D frag layout: col=lane&15, row=(lane>>4)*4+j (m89-verified)
#pragma unroll
            for (int fm = 0; fm < 8; ++fm)
#pragma unroll
                for (int fn = 0; fn < 4; ++fn)
#pragma unroll
                    for (int j = 0; j < 4; ++j) {
                        int r = fm * 16 + lg * 4 + j;        // 0..127
                        int c = wc * 64 + fn * 16 + l15;     // 0..255
                        fl[r * 256 + (c ^ ((r & 7) << 2))] = acc[fm][fn][j];
                    }
        }
        __syncthreads();
        // 128 rows x 8 nodes = 1024 outputs; 512 threads -> 2 each
#pragma unroll 1
        for (int t = 0; t < 2; ++t) {
            int idx = tid + t * 512;
            int r   = idx >> 3;                  // row within half
            int nd  = idx & 7;                   // node within tile
            int node = nt * 8 + nd;

            float z[32];
            const float* q0 = bias0 + node * 32;
#pragma unroll
            for (int q = 0; q < 8; ++q) {
                int cf = (nd * 32 + q * 4) ^ ((r & 7) << 2);
                float4 v  = *(const float4*)(fl + r * 256 + cf);
                float4 bb = *(const float4*)(q0 + q * 4);
                z[q * 4 + 0] = v.x + bb.x;
                z[q * 4 + 1] = v.y + bb.y;
                z[q * 4 + 2] = v.z + bb.z;
                z[q * 4 + 3] = v.w + bb.w;
            }
            if (bias1 != nullptr) {
                const float* q1 = bias1 + node * 32;
#pragma unroll
                for (int q = 0; q < 8; ++q) {
                    float4 bb = *(const float4*)(q1 + q * 4);
                    z[q * 4 + 0] += bb.x; z[q * 4 + 1] += bb.y;
                    z[q * 4 + 2] += bb.z; z[q * 4 + 3] += bb.w;
                }
            }

            float h1v[15];
#pragma unroll
            for (int j = 0; j < 15; ++j) {
                // one-hot layer code == adding col (32+layer) of Dw1 to bias
                float a = Db1[j] + Dw1[j * 35 + 32 + layer];
#pragma unroll
                for (int c = 0; c < 32; ++c) a += z[c] * Dw1[j * 35 + c];
                h1v[j] = fmaxf(a, 0.01f * a);
            }
            float h2v[8];
#pragma unroll
            for (int j = 0; j < 8; ++j) {
                float a = Db2[j];
#pragma unroll
                for (int c = 0; c < 15; ++c) a += h1v[c] * Dw2[j * 15 + c];
                h2v[j] = fmaxf(a, 0.01f * a);
            }
            float o = Db3[0];
#pragma unroll
            for (int c = 0; c < 8; ++c) o += h2v[c] * Dw3[c];

            int rg = mt * 256 + half * 128 + r;
            out[(size_t)rg * 1024 + node] = fmaxf(o, 0.01f * o);
        }
    }
}

extern "C" void kernel_launch(void* const* d_in, const int* in_sizes, int n_in,
                              void* d_out, int out_size, void* d_ws, size_t ws_size,
                              hipStream_t stream) {
    const float* x    = (const float*)d_in[0];
    const float* W0   = (const float*)d_in[1];
    const float* b0   = (const float*)d_in[2];
    const float* W1   = (const float*)d_in[3];
    const float* b1   = (const float*)d_in[4];
    const float* W2   = (const float*)d_in[5];
    const float* b2   = (const float*)d_in[6];
    const float* Ws02 = (const float*)d_in[7];
    const float* bs02 = (const float*)d_in[8];
    const float* Ws13 = (const float*)d_in[9];
    const float* bs13 = (const float*)d_in[10];
    const float* Dw1  = (const float*)d_in[11];
    const float* Db1  = (const float*)d_in[12];
    const float* Dw2  = (const float*)d_in[13];
    const float* Db2  = (const float*)d_in[14];
    const float* Dw3  = (const float*)d_in[15];
    const float* Db3  = (const float*)d_in[16];
    float* out = (float*)d_out;

    // workspace: h0 [512][1024] f32 (2 MiB) | h1 (2 MiB)
    float* h0 = (float*)d_ws;
    float* h1 = h0 + 512 * 1024;

    const dim3 gg(256), gb(512);       // (512/256)*(32768/256) output tiles
    const size_t LDS = 128 * 1024;     // 2 x 64 KiB K-tile buffers / epilogue

    // layer 0: pre0 = x*W0^T -> DAN(l=0) -> h0           (K=1024: 32 tiles)
    gemm_dan<<<gg, gb, LDS, stream>>>(x, nullptr, W0, nullptr, b0, nullptr,
                                      Dw1, Db1, Dw2, Db2, Dw3, Db3, h0, 32, 32, 0);
    // layer 1: pre1 = h0*W1^T + x*Ws02^T -> DAN(l=1) -> h1 (K=2048: 64 tiles)
    gemm_dan<<<gg, gb, LDS, stream>>>(h0, x, W1, Ws02, b1, bs02,
                                      Dw1, Db1, Dw2, Db2, Dw3, Db3, h1, 64, 32, 1);
    // layer 2: pre2 = h1*W2^T + h0*Ws13^T -> DAN(l=2) -> out
    gemm_dan<<<gg, gb, LDS, stream>>>(h1, h0, W2, Ws13, b2, bs13,
                                      Dw1, Db1, Dw2, Db2, Dw3, Db3, out, 64, 32, 2);
}